// Round 9
// baseline (73.452 us; speedup 1.0000x reference)
//
#include <hip/hip_runtime.h>

#define M_ 256
#define K_ 8192
#define N_ 8192

typedef int v4i __attribute__((ext_vector_type(4)));
typedef int v16i __attribute__((ext_vector_type(16)));

// ---------------- kernel 1: per-token int8 quantization ----------------
// Writes xq in MFMA-A-fragment-tiled layout (bijective byte map, 2 MB):
//   (m,k) -> addr = (mt<<18) + (chunk<<13) + (ks<<10) + (lane<<4) + b
//   mt=m>>5, chunk=k>>8, ks=(k>>5)&7, lane=(m&31)+32*((k>>4)&1), b=k&15
__global__ __launch_bounds__(256) void awq_quant(const float* __restrict__ x,
                                                 signed char* __restrict__ xqt,
                                                 float* __restrict__ scales) {
    const int m = blockIdx.x;
    const int t = threadIdx.x;
    const float4* xrow = (const float4*)(x + (size_t)m * K_);
    float4 v[8];
    float mx = 0.0f;
#pragma unroll
    for (int j = 0; j < 8; ++j) {
        v[j] = xrow[j * 256 + t];
        mx = fmaxf(mx, fmaxf(fmaxf(fabsf(v[j].x), fabsf(v[j].y)),
                             fmaxf(fabsf(v[j].z), fabsf(v[j].w))));
    }
#pragma unroll
    for (int off = 32; off > 0; off >>= 1) mx = fmaxf(mx, __shfl_xor(mx, off, 64));
    __shared__ float red[4];
    if ((t & 63) == 0) red[t >> 6] = mx;
    __syncthreads();
    mx = fmaxf(fmaxf(red[0], red[1]), fmaxf(red[2], red[3]));
    const float scale = fmaxf(mx / 127.0f, 1e-8f);

    char* base = (char*)xqt + ((size_t)(m >> 5) << 18);
    const int ml = m & 31;
#pragma unroll
    for (int j = 0; j < 8; ++j) {
        const int q0 = (int)fminf(fmaxf(rintf(v[j].x / scale), -127.0f), 127.0f);
        const int q1 = (int)fminf(fmaxf(rintf(v[j].y / scale), -127.0f), 127.0f);
        const int q2 = (int)fminf(fmaxf(rintf(v[j].z / scale), -127.0f), 127.0f);
        const int q3 = (int)fminf(fmaxf(rintf(v[j].w / scale), -127.0f), 127.0f);
        const int packed = (q0 & 255) | ((q1 & 255) << 8) | ((q2 & 255) << 16) | ((q3 & 255) << 24);
        const int k0 = 4 * (j * 256 + t);
        const int addr = ((k0 >> 8) << 13) + (((k0 >> 5) & 7) << 10) +
                         ((ml + (((k0 >> 4) & 1) << 5)) << 4) + (k0 & 15);
        *(int*)(base + addr) = packed;
    }
    if (t == 0) scales[m] = scale;
}

// byte-transpose: 4 k-rows (w0..w3), cols j=0..3 -> dword per col at +j*272
__device__ __forceinline__ void stage_b(char* btn, int bwo,
                                        const int4& w0, const int4& w1,
                                        const int4& w2, const int4& w3) {
    const int* p0 = (const int*)&w0;
    const int* p1 = (const int*)&w1;
    const int* p2 = (const int*)&w2;
    const int* p3 = (const int*)&w3;
#pragma unroll
    for (int j = 0; j < 4; ++j) {
        const unsigned u = __builtin_amdgcn_perm((unsigned)p1[j], (unsigned)p0[j], 0x00000400u);
        const unsigned w = __builtin_amdgcn_perm((unsigned)p3[j], (unsigned)p2[j], 0x00000400u);
        const unsigned o = __builtin_amdgcn_perm(w, u, 0x05040100u);
        *(unsigned*)(btn + bwo + j * 272) = o;
    }
}

// ---------------- kernel 2a: split-K int8 GEMM (BN=64), raw partials ------
// grid = 256 = 128 n-stripes x 2 k-halves. 512 thr = 8 waves, each wave one
// 32x32 m-tile x TWO n-subtiles (shared A frags). Each block reads a private
// [4096 k x 256B] stripe of qw -> 256B DRAM granules (2x round-6), traffic
// still exactly-once. 16 phases, round-6 pipeline: refill-A (L2) before
// loadq (HBM); one raw barrier/phase; lgkmcnt-only drain, never vmcnt(0).
// Epilogue stores raw int sums as fp32 partials (exact, < 2^24).
__global__ __launch_bounds__(512, 2) void awq_gemm64(const signed char* __restrict__ xqt,
                                                     const int* __restrict__ qw,
                                                     float* __restrict__ part) {
    __shared__ __align__(16) char btile[2][64 * 272];
    const int t = threadIdx.x;
    const int lane = t & 63;
    const int wave = t >> 6;
    const int bid = blockIdx.x;
    const int kh = bid & 1;                 // k-half
    const int n0 = (bid >> 1) * 64;         // n-stripe

    const int cg = t & 15;                  // col-group: cols n0 + 4*cg + j
    const int q0 = t >> 4;                  // 0..31: row-quads q0, q0+32
    const int* qbase = qw + ((size_t)(kh * 4096 + 4 * q0)) * N_ + n0 + 4 * cg;

    // tiled A base: wave's m-tile (256KB each), this lane's 16B slot
    const signed char* xqb = xqt + ((size_t)wave << 18) + lane * 16;

    const int bro0 = (lane & 31) * 272 + (lane >> 5) * 16;        // nt=0
    const int bro1 = (32 + (lane & 31)) * 272 + (lane >> 5) * 16; // nt=1
    const int bwo = (4 * cg) * 272 + 4 * q0;

    v16i acc0 = {}, acc1 = {};
    v4i aE[8], aO[8];
    int4 sA[8], sB[8];

    auto loadq = [&](int4* dst, int p) {    // local phase p: 256 k-rows
        const int* q = qbase + (size_t)p * 256 * N_;
#pragma unroll
        for (int qd = 0; qd < 2; ++qd)
#pragma unroll
            for (int i = 0; i < 4; ++i)
                dst[qd * 4 + i] = *(const int4*)(q + (size_t)(128 * qd + i) * N_);
    };
    auto loada = [&](v4i* a, int p) {       // global chunk kh*16+p
#pragma unroll
        for (int f = 0; f < 8; ++f)
            a[f] = *(const v4i*)(xqb + (size_t)(kh * 16 + p) * 8192 + f * 1024);
    };
    auto stage64 = [&](char* btn, const int4* w) {
        stage_b(btn, bwo, w[0], w[1], w[2], w[3]);
        stage_b(btn, bwo + 128, w[4], w[5], w[6], w[7]);
    };

    // prologue
    loadq(sA, 0);
    loadq(sB, 1);
    loada(aE, 0);
    stage64(&btile[0][0], sA);
    asm volatile("s_waitcnt lgkmcnt(0)" ::: "memory");
    __builtin_amdgcn_s_barrier();
    __builtin_amdgcn_sched_barrier(0);

    for (int p = 0; p < 16; p += 2) {
        {   // even: compute p (buf0, aE); refill aO<-p+1; loadq sA<-p+2; stage sB->buf1
            loada(aO, (p + 1 < 16) ? p + 1 : 15);
            loadq(sA, (p + 2 < 16) ? p + 2 : 15);
            __builtin_amdgcn_sched_barrier(0);
            const char* btc = &btile[0][0];
#pragma unroll
            for (int f = 0; f < 8; ++f) {
                const v4i b0 = *(const v4i*)(btc + bro0 + f * 32);
                acc0 = __builtin_amdgcn_mfma_i32_32x32x32_i8(aE[f], b0, acc0, 0, 0, 0);
                const v4i b1 = *(const v4i*)(btc + bro1 + f * 32);
                acc1 = __builtin_amdgcn_mfma_i32_32x32x32_i8(aE[f], b1, acc1, 0, 0, 0);
            }
            stage64(&btile[1][0], sB);
            asm volatile("s_waitcnt lgkmcnt(0)" ::: "memory");
            __builtin_amdgcn_s_barrier();
            __builtin_amdgcn_sched_barrier(0);
        }
        {   // odd: compute p+1 (buf1, aO); refill aE<-p+2; loadq sB<-p+3; stage sA->buf0
            loada(aE, (p + 2 < 16) ? p + 2 : 15);
            loadq(sB, (p + 3 < 16) ? p + 3 : 15);
            __builtin_amdgcn_sched_barrier(0);
            const char* btc = &btile[1][0];
#pragma unroll
            for (int f = 0; f < 8; ++f) {
                const v4i b0 = *(const v4i*)(btc + bro0 + f * 32);
                acc0 = __builtin_amdgcn_mfma_i32_32x32x32_i8(aO[f], b0, acc0, 0, 0, 0);
                const v4i b1 = *(const v4i*)(btc + bro1 + f * 32);
                acc1 = __builtin_amdgcn_mfma_i32_32x32x32_i8(aO[f], b1, acc1, 0, 0, 0);
            }
            stage64(&btile[0][0], sA);
            asm volatile("s_waitcnt lgkmcnt(0)" ::: "memory");
            __builtin_amdgcn_s_barrier();
            __builtin_amdgcn_sched_barrier(0);
        }
    }

    // epilogue: raw partial sums. C/D: col=lane&31, row=(g&3)+8*(g>>2)+4*(lane>>5)
    float* pb = part + (size_t)kh * M_ * N_;
    const int mb = wave * 32 + 4 * (lane >> 5);
#pragma unroll
    for (int g = 0; g < 16; ++g) {
        const int m = mb + (g & 3) + 8 * (g >> 2);
        pb[(size_t)m * N_ + n0 + (lane & 31)]      = (float)acc0[g];
        pb[(size_t)m * N_ + n0 + 32 + (lane & 31)] = (float)acc1[g];
    }
}

// ---------------- kernel 2b: fallback full-K GEMM (round-6 best) ----------
__global__ __launch_bounds__(512) void awq_gemm32(const signed char* __restrict__ xqt,
                                                  const float* __restrict__ scales,
                                                  const int* __restrict__ qw,
                                                  const float* __restrict__ wscale,
                                                  const float* __restrict__ bias,
                                                  float* __restrict__ out) {
    __shared__ __align__(16) char btile[2][32 * 272];
    const int t = threadIdx.x;
    const int lane = t & 63;
    const int wave = t >> 6;
    const int n0 = blockIdx.x * 32;
    const int sa = t & 7;
    const int sr = t >> 3;
    const int* qbase = qw + (size_t)(4 * sr) * N_ + n0 + 4 * sa;
    const signed char* xqb = xqt + ((size_t)wave << 18) + lane * 16;
    const int bro = (lane & 31) * 272 + (lane >> 5) * 16;
    const int bwo = (4 * sa) * 272 + 4 * sr;

    v16i acc = {};
    v4i aE[8], aO[8];
    int4 sA[4], sB[4];
    auto loadq = [&](int4* dst, int chunk) {
        const int4* q = (const int4*)(qbase + (size_t)chunk * 256 * N_);
        dst[0] = q[0]; dst[1] = q[N_ / 4]; dst[2] = q[2 * (N_ / 4)]; dst[3] = q[3 * (N_ / 4)];
    };
#pragma unroll
    for (int ks = 0; ks < 8; ++ks) aE[ks] = *(const v4i*)(xqb + ks * 1024);
    loadq(sA, 0);
    loadq(sB, 1);
    stage_b(&btile[0][0], bwo, sA[0], sA[1], sA[2], sA[3]);
    asm volatile("s_waitcnt lgkmcnt(0)" ::: "memory");
    __builtin_amdgcn_s_barrier();
    __builtin_amdgcn_sched_barrier(0);

    for (int sc = 0; sc < 32; sc += 2) {
        {
            const int ra = (sc + 1 < 32) ? sc + 1 : 31;
#pragma unroll
            for (int ks = 0; ks < 8; ++ks)
                aO[ks] = *(const v4i*)(xqb + ra * 8192 + ks * 1024);
            loadq(sA, (sc + 2 < 32) ? sc + 2 : 31);
            __builtin_amdgcn_sched_barrier(0);
            const char* btc = &btile[0][0];
#pragma unroll
            for (int ks = 0; ks < 8; ++ks) {
                const v4i bf = *(const v4i*)(btc + bro + ks * 32);
                acc = __builtin_amdgcn_mfma_i32_32x32x32_i8(aE[ks], bf, acc, 0, 0, 0);
            }
            stage_b(&btile[1][0], bwo, sB[0], sB[1], sB[2], sB[3]);
            asm volatile("s_waitcnt lgkmcnt(0)" ::: "memory");
            __builtin_amdgcn_s_barrier();
            __builtin_amdgcn_sched_barrier(0);
        }
        {
            const int ra = (sc + 2 < 32) ? sc + 2 : 31;
#pragma unroll
            for (int ks = 0; ks < 8; ++ks)
                aE[ks] = *(const v4i*)(xqb + ra * 8192 + ks * 1024);
            loadq(sB, (sc + 3 < 32) ? sc + 3 : 31);
            __builtin_amdgcn_sched_barrier(0);
            const char* btc = &btile[1][0];
#pragma unroll
            for (int ks = 0; ks < 8; ++ks) {
                const v4i bf = *(const v4i*)(btc + bro + ks * 32);
                acc = __builtin_amdgcn_mfma_i32_32x32x32_i8(aO[ks], bf, acc, 0, 0, 0);
            }
            stage_b(&btile[0][0], bwo, sA[0], sA[1], sA[2], sA[3]);
            asm volatile("s_waitcnt lgkmcnt(0)" ::: "memory");
            __builtin_amdgcn_s_barrier();
            __builtin_amdgcn_sched_barrier(0);
        }
    }
    const int n = n0 + (lane & 31);
    const float wn = wscale[n];
    const float bn = bias[n];
    const int mb = wave * 32 + 4 * (lane >> 5);
#pragma unroll
    for (int g = 0; g < 16; ++g) {
        const int m = mb + (g & 3) + 8 * (g >> 2);
        out[(size_t)m * N_ + n] = ((float)acc[g] * scales[m]) * wn + bn;
    }
}

// ---------------- kernel 3: split-K reduce + dequant epilogue -------------
__global__ __launch_bounds__(256) void awq_reduce(const float* __restrict__ p0,
                                                  const float* __restrict__ p1,
                                                  const float* __restrict__ scales,
                                                  const float* __restrict__ wsc,
                                                  const float* __restrict__ bias,
                                                  float* __restrict__ out) {
    const int idx = blockIdx.x * 256 + threadIdx.x;   // float4 index
    const float4 a = ((const float4*)p0)[idx];
    const float4 b = ((const float4*)p1)[idx];
    const int n4 = (idx * 4) & (N_ - 1);
    const int m = idx >> 11;                          // (idx*4)/N_
    const float as = scales[m];
    const float4 w = *(const float4*)(wsc + n4);
    const float4 bi = *(const float4*)(bias + n4);
    float4 o;
    o.x = ((a.x + b.x) * as) * w.x + bi.x;
    o.y = ((a.y + b.y) * as) * w.y + bi.y;
    o.z = ((a.z + b.z) * as) * w.z + bi.z;
    o.w = ((a.w + b.w) * as) * w.w + bi.w;
    ((float4*)out)[idx] = o;
}

extern "C" void kernel_launch(void* const* d_in, const int* in_sizes, int n_in,
                              void* d_out, int out_size, void* d_ws, size_t ws_size,
                              hipStream_t stream) {
    const float* x    = (const float*)d_in[0];
    const int*   qw   = (const int*)d_in[1];
    const float* wsc  = (const float*)d_in[2];
    const float* bias = (const float*)d_in[3];
    float* out = (float*)d_out;

    signed char* xqbuf  = (signed char*)d_ws;                        // 2 MB, tiled
    float*       scales = (float*)((char*)d_ws + (2u << 20));        // 1 KB
    float*       part   = (float*)((char*)d_ws + (4u << 20));        // 2 x 8 MB

    awq_quant<<<M_, 256, 0, stream>>>(x, xqbuf, scales);
    if (ws_size >= (20u << 20)) {
        awq_gemm64<<<256, 512, 0, stream>>>(xqbuf, qw, part);
        awq_reduce<<<(M_ * N_ / 4) / 256, 256, 0, stream>>>(
            part, part + (size_t)M_ * N_, scales, wsc, bias, out);
    } else {
        awq_gemm32<<<N_ / 32, 512, 0, stream>>>(xqbuf, scales, qw, wsc, bias, out);
    }
}

// Round 10
// 72.466 us; speedup vs baseline: 1.0136x; 1.0136x over previous
//
#include <hip/hip_runtime.h>

#define M_ 256
#define K_ 8192
#define N_ 8192

typedef int v4i __attribute__((ext_vector_type(4)));
typedef int v16i __attribute__((ext_vector_type(16)));
typedef long v2l __attribute__((ext_vector_type(2)));

// 16B nontemporal load (nt flag: no L1 allocation; L2 unaffected)
__device__ __forceinline__ int4 ntload16(const int* p) {
    v2l r = __builtin_nontemporal_load((const v2l*)p);
    int4 o;
    *(v2l*)&o = r;
    return o;
}

// ---------------- kernel 1: per-token int8 quantization ----------------
// Writes xq in MFMA-A-fragment-tiled layout (bijective byte map, 2 MB):
//   (m,k) -> addr = (mt<<18) + (chunk<<13) + (ks<<10) + (lane<<4) + b
//   mt=m>>5, chunk=k>>8, ks=(k>>5)&7, lane=(m&31)+32*((k>>4)&1), b=k&15
__global__ __launch_bounds__(256) void awq_quant(const float* __restrict__ x,
                                                 signed char* __restrict__ xqt,
                                                 float* __restrict__ scales) {
    const int m = blockIdx.x;
    const int t = threadIdx.x;
    const float4* xrow = (const float4*)(x + (size_t)m * K_);
    float4 v[8];
    float mx = 0.0f;
#pragma unroll
    for (int j = 0; j < 8; ++j) {
        v[j] = xrow[j * 256 + t];
        mx = fmaxf(mx, fmaxf(fmaxf(fabsf(v[j].x), fabsf(v[j].y)),
                             fmaxf(fabsf(v[j].z), fabsf(v[j].w))));
    }
#pragma unroll
    for (int off = 32; off > 0; off >>= 1) mx = fmaxf(mx, __shfl_xor(mx, off, 64));
    __shared__ float red[4];
    if ((t & 63) == 0) red[t >> 6] = mx;
    __syncthreads();
    mx = fmaxf(fmaxf(red[0], red[1]), fmaxf(red[2], red[3]));
    const float scale = fmaxf(mx / 127.0f, 1e-8f);

    char* base = (char*)xqt + ((size_t)(m >> 5) << 18);
    const int ml = m & 31;
#pragma unroll
    for (int j = 0; j < 8; ++j) {
        const int q0 = (int)fminf(fmaxf(rintf(v[j].x / scale), -127.0f), 127.0f);
        const int q1 = (int)fminf(fmaxf(rintf(v[j].y / scale), -127.0f), 127.0f);
        const int q2 = (int)fminf(fmaxf(rintf(v[j].z / scale), -127.0f), 127.0f);
        const int q3 = (int)fminf(fmaxf(rintf(v[j].w / scale), -127.0f), 127.0f);
        const int packed = (q0 & 255) | ((q1 & 255) << 8) | ((q2 & 255) << 16) | ((q3 & 255) << 24);
        const int k0 = 4 * (j * 256 + t);
        const int addr = ((k0 >> 8) << 13) + (((k0 >> 5) & 7) << 10) +
                         ((ml + (((k0 >> 4) & 1) << 5)) << 4) + (k0 & 15);
        *(int*)(base + addr) = packed;
    }
    if (t == 0) scales[m] = scale;
}

// ---------------- kernel 2: int8 GEMM + dequant epilogue ----------------
// grid = 256 blocks (1/CU), 512 thr = 8 waves, one 32x32 m-tile per wave.
// Round-6 structure (best: 63.9us): 32 phases, A-refill (L2) issued before
// qw loadq (HBM) with aE/aO ping-pong; one raw barrier per phase,
// lgkmcnt-only drain, never vmcnt(0). NEW: qw loads nontemporal (no L1
// alloc -- zero reuse there; halves TCP fill work on the return path),
// out stores nontemporal.

__device__ __forceinline__ void stage_b(char* btn, int bwo,
                                        const int4& w0, const int4& w1,
                                        const int4& w2, const int4& w3) {
    const int* p0 = (const int*)&w0;
    const int* p1 = (const int*)&w1;
    const int* p2 = (const int*)&w2;
    const int* p3 = (const int*)&w3;
#pragma unroll
    for (int j = 0; j < 4; ++j) {
        const unsigned u = __builtin_amdgcn_perm((unsigned)p1[j], (unsigned)p0[j], 0x00000400u);
        const unsigned w = __builtin_amdgcn_perm((unsigned)p3[j], (unsigned)p2[j], 0x00000400u);
        const unsigned o = __builtin_amdgcn_perm(w, u, 0x05040100u);
        *(unsigned*)(btn + bwo + j * 272) = o;
    }
}

__global__ __launch_bounds__(512) void awq_gemm(const signed char* __restrict__ xqt,
                                                const float* __restrict__ scales,
                                                const int* __restrict__ qw,
                                                const float* __restrict__ wscale,
                                                const float* __restrict__ bias,
                                                float* __restrict__ out) {
    __shared__ __align__(16) char btile[2][32 * 272];
    const int t = threadIdx.x;
    const int lane = t & 63;
    const int wave = t >> 6;
    const int n0 = blockIdx.x * 32;

    const int sa = t & 7;                  // n-group
    const int sr = t >> 3;                 // k-row group (0..63)
    const int* qbase = qw + (size_t)(4 * sr) * N_ + n0 + 4 * sa;

    // tiled A base: wave's m-tile (256KB each), this lane's 16B slot
    const signed char* xqb = xqt + ((size_t)wave << 18) + lane * 16;

    const int bro = (lane & 31) * 272 + (lane >> 5) * 16;
    const int bwo = (4 * sa) * 272 + 4 * sr;

    v16i acc = {};
    v4i aE[8], aO[8];
    int4 sA[4], sB[4];

    auto loadq = [&](int4* dst, int chunk) {
        const int* q = qbase + (size_t)chunk * 256 * N_;
        dst[0] = ntload16(q);
        dst[1] = ntload16(q + (size_t)N_);
        dst[2] = ntload16(q + (size_t)2 * N_);
        dst[3] = ntload16(q + (size_t)3 * N_);
    };

    // prologue: aE <- chunk0 frags; sA <- chunk0, sB <- chunk1; stage buf0
#pragma unroll
    for (int ks = 0; ks < 8; ++ks) aE[ks] = *(const v4i*)(xqb + ks * 1024);
    loadq(sA, 0);
    loadq(sB, 1);
    stage_b(&btile[0][0], bwo, sA[0], sA[1], sA[2], sA[3]);
    asm volatile("s_waitcnt lgkmcnt(0)" ::: "memory");
    __builtin_amdgcn_s_barrier();
    __builtin_amdgcn_sched_barrier(0);

    for (int sc = 0; sc < 32; sc += 2) {
        {   // even: compute chunk sc (buf0, aE); refill aO<-sc+1; loadq sA<-sc+2;
            // stage sc+1 (sB) -> buf1
            const int ra = (sc + 1 < 32) ? sc + 1 : 31;
#pragma unroll
            for (int ks = 0; ks < 8; ++ks)
                aO[ks] = *(const v4i*)(xqb + ra * 8192 + ks * 1024);
            const int c2 = (sc + 2 < 32) ? sc + 2 : 31;
            loadq(sA, c2);
            __builtin_amdgcn_sched_barrier(0);
            const char* btc = &btile[0][0];
#pragma unroll
            for (int ks = 0; ks < 8; ++ks) {
                const v4i bf = *(const v4i*)(btc + bro + ks * 32);
                acc = __builtin_amdgcn_mfma_i32_32x32x32_i8(aE[ks], bf, acc, 0, 0, 0);
            }
            stage_b(&btile[1][0], bwo, sB[0], sB[1], sB[2], sB[3]);
            asm volatile("s_waitcnt lgkmcnt(0)" ::: "memory");
            __builtin_amdgcn_s_barrier();
            __builtin_amdgcn_sched_barrier(0);
        }
        {   // odd: compute chunk sc+1 (buf1, aO); refill aE<-sc+2; loadq sB<-sc+3;
            // stage sc+2 (sA) -> buf0
            const int ra = (sc + 2 < 32) ? sc + 2 : 31;
#pragma unroll
            for (int ks = 0; ks < 8; ++ks)
                aE[ks] = *(const v4i*)(xqb + ra * 8192 + ks * 1024);
            const int c3 = (sc + 3 < 32) ? sc + 3 : 31;
            loadq(sB, c3);
            __builtin_amdgcn_sched_barrier(0);
            const char* btc = &btile[1][0];
#pragma unroll
            for (int ks = 0; ks < 8; ++ks) {
                const v4i bf = *(const v4i*)(btc + bro + ks * 32);
                acc = __builtin_amdgcn_mfma_i32_32x32x32_i8(aO[ks], bf, acc, 0, 0, 0);
            }
            stage_b(&btile[0][0], bwo, sA[0], sA[1], sA[2], sA[3]);
            asm volatile("s_waitcnt lgkmcnt(0)" ::: "memory");
            __builtin_amdgcn_s_barrier();
            __builtin_amdgcn_sched_barrier(0);
        }
    }

    // epilogue: dequant. C/D layout: col=lane&31, row=(g&3)+8*(g>>2)+4*(lane>>5)
    const int n = n0 + (lane & 31);
    const float wn = wscale[n];
    const float bn = bias[n];
    const int mb = wave * 32 + 4 * (lane >> 5);
#pragma unroll
    for (int g = 0; g < 16; ++g) {
        const int m = mb + (g & 3) + 8 * (g >> 2);
        __builtin_nontemporal_store(((float)acc[g] * scales[m]) * wn + bn,
                                    &out[(size_t)m * N_ + n]);
    }
}

extern "C" void kernel_launch(void* const* d_in, const int* in_sizes, int n_in,
                              void* d_out, int out_size, void* d_ws, size_t ws_size,
                              hipStream_t stream) {
    const float* x    = (const float*)d_in[0];
    const int*   qw   = (const int*)d_in[1];
    const float* wsc  = (const float*)d_in[2];
    const float* bias = (const float*)d_in[3];
    float* out = (float*)d_out;

    signed char* xqbuf  = (signed char*)d_ws;                      // 2 MB, tiled
    float*       scales = (float*)((char*)d_ws + (size_t)M_ * K_); // 1 KB

    awq_quant<<<M_, 256, 0, stream>>>(x, xqbuf, scales);
    awq_gemm<<<N_ / 32, 512, 0, stream>>>(xqbuf, scales, qw, wsc, bias, out);
}